// Round 15
// baseline (551.318 us; speedup 1.0000x reference)
//
#include <hip/hip_runtime.h>

#define N_TOK 8192
#define DDIM  1024
#define HDIM  4096
#define NEXP  6
#define RBLOCKS (N_TOK / 4)
#define SBLOCKS 32

typedef unsigned short ushort_t;
typedef __bf16 bf16_t;
typedef bf16_t bf16x8 __attribute__((ext_vector_type(8)));
typedef float f32x4 __attribute__((ext_vector_type(4)));

typedef const __attribute__((address_space(1))) void* gptr_t;
typedef __attribute__((address_space(3))) void* lptr_t;

__device__ __forceinline__ void g2l16(const void* g, void* l) {
    __builtin_amdgcn_global_load_lds((gptr_t)g, (lptr_t)l, 16, 0, 0);
}

__device__ __forceinline__ ushort_t f2bf(float f) {
    unsigned int u = __float_as_uint(f);
    unsigned int r = (u + 0x7FFFu + ((u >> 16) & 1u)) >> 16;
    return (ushort_t)r;
}

// ---------------- transpose + convert: src (R,C) fp32 -> dst (C,R) bf16, per expert z ----------------
__global__ void transpose_bf16_kernel(const float* __restrict__ src, ushort_t* __restrict__ dst,
                                      int R, int C) {
    __shared__ float tile[32][33];
    size_t msz = (size_t)R * C;
    src += (size_t)blockIdx.z * msz;
    dst += (size_t)blockIdx.z * msz;
    int c0 = blockIdx.x * 32, r0 = blockIdx.y * 32;
    int tx = threadIdx.x & 31, ty = threadIdx.x >> 5;
#pragma unroll
    for (int i = 0; i < 4; ++i)
        tile[ty + 8 * i][tx] = src[(size_t)(r0 + ty + 8 * i) * C + c0 + tx];
    __syncthreads();
#pragma unroll
    for (int i = 0; i < 4; ++i)
        dst[(size_t)(c0 + ty + 8 * i) * R + r0 + tx] = f2bf(tile[tx][ty + 8 * i]);
}

// ---------------- router (also emits xb = bf16(x)) ----------------
__global__ void router_kernel(const float* __restrict__ x, const float* __restrict__ wr,
                              ushort_t* __restrict__ xb,
                              int* __restrict__ tok_e, float* __restrict__ tok_w,
                              float* __restrict__ part_p, int* __restrict__ part_c) {
    __shared__ float bsum[NEXP];
    __shared__ int bcnt[NEXP];
    int wid = threadIdx.x >> 6, l = threadIdx.x & 63;
    if (threadIdx.x < NEXP) { bsum[threadIdx.x] = 0.f; bcnt[threadIdx.x] = 0; }
    __syncthreads();
    int t = blockIdx.x * 4 + wid;
    const float* xr = x + (size_t)t * DDIM;
    ushort_t* xbr = xb + (size_t)t * DDIM;
    float acc[NEXP] = {0.f, 0.f, 0.f, 0.f, 0.f, 0.f};
#pragma unroll
    for (int c = 0; c < 4; ++c) {
        int k0 = c * 256 + l * 4;
        float4 xv = *(const float4*)(xr + k0);
        union { ushort_t u[4]; uint2 v; } ob;
        ob.u[0] = f2bf(xv.x); ob.u[1] = f2bf(xv.y); ob.u[2] = f2bf(xv.z); ob.u[3] = f2bf(xv.w);
        *(uint2*)(xbr + k0) = ob.v;
        float wv[24];
#pragma unroll
        for (int q = 0; q < 6; ++q)
            *(float4*)(wv + 4 * q) = *(const float4*)(wr + (size_t)k0 * NEXP + 4 * q);
        float xa[4] = {xv.x, xv.y, xv.z, xv.w};
#pragma unroll
        for (int r = 0; r < 4; ++r)
#pragma unroll
            for (int e = 0; e < NEXP; ++e) acc[e] += xa[r] * wv[r * NEXP + e];
    }
#pragma unroll
    for (int e = 0; e < NEXP; ++e)
#pragma unroll
        for (int d = 32; d >= 1; d >>= 1) acc[e] += __shfl_xor(acc[e], d);
    if (l == 0) {
        float m = acc[0];
#pragma unroll
        for (int e = 1; e < NEXP; ++e) m = fmaxf(m, acc[e]);
        float p[NEXP], s = 0.f;
#pragma unroll
        for (int e = 0; e < NEXP; ++e) { p[e] = expf(acc[e] - m); s += p[e]; }
        float inv = 1.0f / s;
#pragma unroll
        for (int e = 0; e < NEXP; ++e) p[e] *= inv;
        int i1 = 0; float b1 = p[0];
#pragma unroll
        for (int e = 1; e < NEXP; ++e) if (p[e] > b1) { b1 = p[e]; i1 = e; }
        int i2 = -1; float b2 = -1.f;
#pragma unroll
        for (int e = 0; e < NEXP; ++e) if (e != i1 && p[e] > b2) { b2 = p[e]; i2 = e; }
        float swn = 1.0f / (b1 + b2);
        tok_e[2 * t] = i1; tok_e[2 * t + 1] = i2;
        tok_w[2 * t] = b1 * swn; tok_w[2 * t + 1] = b2 * swn;
        atomicAdd(&bcnt[i1], 1);
        atomicAdd(&bcnt[i2], 1);
#pragma unroll
        for (int e = 0; e < NEXP; ++e) atomicAdd(&bsum[e], p[e]);
    }
    __syncthreads();
    if (threadIdx.x < NEXP) {
        part_p[(size_t)blockIdx.x * NEXP + threadIdx.x] = bsum[threadIdx.x];
        part_c[(size_t)blockIdx.x * NEXP + threadIdx.x] = bcnt[threadIdx.x];
    }
}

// ---------------- finalize ----------------
__global__ void finalize_kernel(const float* __restrict__ part_p, const int* __restrict__ part_c,
                                int* __restrict__ counts, int* __restrict__ offs,
                                float* __restrict__ aux_out) {
    __shared__ float redp[NEXP][4];
    __shared__ int redc[NEXP][4];
    int tid = threadIdx.x, wid = tid >> 6, l = tid & 63;
    float myp[NEXP] = {0.f, 0.f, 0.f, 0.f, 0.f, 0.f};
    int myc[NEXP] = {0, 0, 0, 0, 0, 0};
    for (int b = tid; b < RBLOCKS; b += 256) {
#pragma unroll
        for (int e = 0; e < NEXP; ++e) {
            myp[e] += part_p[(size_t)b * NEXP + e];
            myc[e] += part_c[(size_t)b * NEXP + e];
        }
    }
#pragma unroll
    for (int e = 0; e < NEXP; ++e) {
#pragma unroll
        for (int d = 32; d >= 1; d >>= 1) {
            myp[e] += __shfl_xor(myp[e], d);
            myc[e] += __shfl_xor(myc[e], d);
        }
        if (l == 0) { redp[e][wid] = myp[e]; redc[e][wid] = myc[e]; }
    }
    __syncthreads();
    if (tid == 0) {
        int o = 0;
        float s = 0.f;
        for (int e = 0; e < NEXP; ++e) {
            int c = redc[e][0] + redc[e][1] + redc[e][2] + redc[e][3];
            float ps = redp[e][0] + redp[e][1] + redp[e][2] + redp[e][3];
            counts[e] = c;
            offs[e] = o;
            o += c;
            float d = ps / (float)N_TOK - (1.0f / 6.0f);
            s += d * d;
        }
        offs[NEXP] = o;
        aux_out[0] = 0.01f * (s / 6.0f);
    }
}

// ---------------- scatter ----------------
__global__ void scatter_kernel(const int* __restrict__ tok_e, const float* __restrict__ tok_w,
                               const int* __restrict__ offs, int* __restrict__ cursors,
                               int* __restrict__ slot_token, float* __restrict__ slot_w) {
    __shared__ int lcnt[NEXP], lbase[NEXP];
    int tid = threadIdx.x;
    if (tid < NEXP) lcnt[tid] = 0;
    __syncthreads();
    int t = blockIdx.x * 256 + tid;
    int e0 = tok_e[2 * t], e1 = tok_e[2 * t + 1];
    int r0 = atomicAdd(&lcnt[e0], 1);
    int r1 = atomicAdd(&lcnt[e1], 1);
    __syncthreads();
    if (tid < NEXP) lbase[tid] = atomicAdd(&cursors[tid], lcnt[tid]);
    __syncthreads();
    int i0 = offs[e0] + lbase[e0] + r0;
    slot_token[i0] = t; slot_w[i0] = tok_w[2 * t];
    int i1 = offs[e1] + lbase[e1] + r1;
    slot_token[i1] = t; slot_w[i1] = tok_w[2 * t + 1];
}

// ---- MoE GEMM: 256M x 256N tile, BK=32, 512 thr / 8 waves (4M x 2N), wave-tile 64x128 ----
// Same per-wave instruction mix and depth-2 counted-vmcnt pipeline as R7 (session best),
// but one barrier domain per CU instead of two: halves block-step count (68K -> 34K).
// 3 LDS buffers x 32KB = 96KB -> 1 block/CU, 8 waves/CU (same wave count as R7).
// Stage = 4 g2l16/thread -> counted vmcnt(4).
// LAYER 1: h = gelu(gather(x) @ w1t^T), Kd=1024, Nd=4096
// LAYER 2: out += w * (hbuf @ w2t^T),   Kd=4096, Nd=1024

#define STAGE(BI, KTE) do { \
    ushort_t* bA_ = sbase + (BI) * 16384; \
    ushort_t* bB_ = bA_ + 8192; \
    g2l16(A + aoff[0] + (KTE),   bA_ + wid * 512); \
    g2l16(A + aoff[1] + (KTE),   bA_ + 4096 + wid * 512); \
    g2l16(Bte + boff[0] + (KTE), bB_ + wid * 512); \
    g2l16(Bte + boff[1] + (KTE), bB_ + 4096 + wid * 512); \
  } while (0)

template <int LAYER>
__global__ __launch_bounds__(512, 1)
void moe_gemm_kernel(const ushort_t* __restrict__ A, const ushort_t* __restrict__ Bt,
                     ushort_t* __restrict__ Hout, float* __restrict__ Out,
                     const int* __restrict__ slot_token, const float* __restrict__ slot_w,
                     const int* __restrict__ offs, const int* __restrict__ counts) {
    constexpr int Kd = (LAYER == 1) ? DDIM : HDIM;
    constexpr int Nd = (LAYER == 1) ? HDIM : DDIM;
    constexpr int NT = Kd / 32;
    extern __shared__ __align__(16) char smem[];
    ushort_t* sbase = (ushort_t*)smem;          // 3 buffers x 16384 elems (A 8192 + B 8192)

    const int e = blockIdx.z;
    const int cnt = counts[e];
    const int mbase = blockIdx.y * 256;
    if (mbase >= cnt) return;                    // block-uniform: safe with raw barriers
    const int nbase = blockIdx.x * 256;
    const int off = offs[e];
    const ushort_t* Bte = Bt + (size_t)e * ((size_t)Nd * Kd);

    const int tid = threadIdx.x;
    const int wid = tid >> 6, l = tid & 63;

    // ---- staging sources (chunk = 8 elems = 16B; cs pre-swizzled, LDS dest linear) ----
    size_t aoff[2], boff[2];
#pragma unroll
    for (int j = 0; j < 2; ++j) {
        int p = j * 512 + tid;
        int row = p >> 2, slot = p & 3;
        int cs = slot ^ ((row >> 1) & 3);
        int gr = mbase + row;
        int grc = gr < cnt - 1 ? gr : cnt - 1;
        size_t arow = (LAYER == 1) ? (size_t)slot_token[off + grc] * DDIM
                                   : (size_t)(off + grc) * HDIM;
        aoff[j] = arow + (size_t)cs * 8;
        boff[j] = (size_t)(nbase + row) * Kd + (size_t)cs * 8;
    }

    // ---- fragment read byte-offsets (swizzled to match) ----
    const int lm = l & 15, kg = l >> 4;
    const int wm = (wid >> 1) * 64, wn = (wid & 1) * 128;
    int aOffs[4], bOffs[8];
#pragma unroll
    for (int fr = 0; fr < 4; ++fr) {
        int ar = wm + fr * 16 + lm;
        aOffs[fr] = ar * 64 + ((kg ^ ((ar >> 1) & 3)) << 4);
    }
#pragma unroll
    for (int fr = 0; fr < 8; ++fr) {
        int br = wn + fr * 16 + lm;
        bOffs[fr] = 16384 + br * 64 + ((kg ^ ((br >> 1) & 3)) << 4);
    }

    f32x4 acc[4][8] = {};

    // ---- prologue: stage tiles 0 and 1 ----
    STAGE(0, 0);
    STAGE(1, 32);
    asm volatile("s_waitcnt vmcnt(4)" ::: "memory");   // tile 0 resident
    __builtin_amdgcn_sched_barrier(0);
    __builtin_amdgcn_s_barrier();

    int rb = 0;
    for (int t = 0; t < NT; ++t) {
        int sb = rb + 2; if (sb >= 3) sb -= 3;
        if (t + 2 < NT) STAGE(sb, (t + 2) * 32);
        const char* bA = (const char*)(sbase + rb * 16384);
        bf16x8 af[4], bfv[8];
#pragma unroll
        for (int fr = 0; fr < 4; ++fr) af[fr] = *(const bf16x8*)(bA + aOffs[fr]);
#pragma unroll
        for (int fr = 0; fr < 8; ++fr) bfv[fr] = *(const bf16x8*)(bA + bOffs[fr]);
#pragma unroll
        for (int i = 0; i < 4; ++i)
#pragma unroll
            for (int n = 0; n < 8; ++n)
                acc[i][n] = __builtin_amdgcn_mfma_f32_16x16x32_bf16(af[i], bfv[n], acc[i][n], 0, 0, 0);
        if (t < NT - 1) {
            if (t + 3 <= NT) { asm volatile("s_waitcnt vmcnt(4)" ::: "memory"); }
            else             { asm volatile("s_waitcnt vmcnt(0)" ::: "memory"); }
            __builtin_amdgcn_sched_barrier(0);
            __builtin_amdgcn_s_barrier();
        }
        rb = rb + 1; if (rb >= 3) rb -= 3;
    }

    // ---- epilogue. C/D: col = lane&15, row = (lane>>4)*4 + reg ----
    if (LAYER == 1) {
#pragma unroll
        for (int i = 0; i < 4; ++i) {
#pragma unroll
            for (int r = 0; r < 4; ++r) {
                int grow = mbase + wm + i * 16 + kg * 4 + r;
                if (grow < cnt) {
                    size_t hbase = (size_t)(off + grow) * HDIM + nbase + wn + lm;
#pragma unroll
                    for (int n = 0; n < 8; ++n) {
                        float v = acc[i][n][r];
                        float u = -1.5957691216f * v * (1.0f + 0.044715f * v * v);
                        float g = v / (1.0f + __expf(u));
                        Hout[hbase + n * 16] = f2bf(g);
                    }
                }
            }
        }
    } else {
#pragma unroll
        for (int i = 0; i < 4; ++i) {
#pragma unroll
            for (int r = 0; r < 4; ++r) {
                int grow = mbase + wm + i * 16 + kg * 4 + r;
                if (grow < cnt) {
                    int si = off + grow;
                    int tok = slot_token[si];
                    float wgt = slot_w[si];
                    float* obase = Out + (size_t)tok * DDIM + nbase + wn + lm;
#pragma unroll
                    for (int n = 0; n < 8; ++n)
                        atomicAdd(obase + n * 16, wgt * acc[i][n][r]);
                }
            }
        }
    }
}
#undef STAGE

extern "C" void kernel_launch(void* const* d_in, const int* in_sizes, int n_in,
                              void* d_out, int out_size, void* d_ws, size_t ws_size,
                              hipStream_t stream) {
    const float* x  = (const float*)d_in[0];
    const float* wr = (const float*)d_in[1];
    const float* w1 = (const float*)d_in[2];
    const float* w2 = (const float*)d_in[3];
    float* out = (float*)d_out;

    char* ws = (char*)d_ws;
    size_t o = 0;
    ushort_t* xb   = (ushort_t*)(ws + o); o += (size_t)N_TOK * DDIM * 2;
    ushort_t* w1t  = (ushort_t*)(ws + o); o += (size_t)NEXP * HDIM * DDIM * 2;
    ushort_t* w2t  = (ushort_t*)(ws + o); o += (size_t)NEXP * DDIM * HDIM * 2;
    ushort_t* hbuf = (ushort_t*)(ws + o); o += (size_t)2 * N_TOK * HDIM * 2;
    int*   tok_e   = (int*)(ws + o);   o += (size_t)N_TOK * 2 * 4;
    float* tok_w   = (float*)(ws + o); o += (size_t)N_TOK * 2 * 4;
    int*   slot_token = (int*)(ws + o);   o += (size_t)2 * N_TOK * 4;
    float* slot_w     = (float*)(ws + o); o += (size_t)2 * N_TOK * 4;
    float* part_p  = (float*)(ws + o); o += (size_t)RBLOCKS * NEXP * 4;
    int*   part_c  = (int*)(ws + o);   o += (size_t)RBLOCKS * NEXP * 4;
    int*   counts  = (int*)(ws + o);   o += 32;
    int*   cursors = (int*)(ws + o);   o += 32;
    int*   offs    = (int*)(ws + o);   o += 32;

    hipMemsetAsync(d_out, 0, (size_t)out_size * sizeof(float), stream);
    hipMemsetAsync(cursors, 0, 32, stream);

    hipFuncSetAttribute((const void*)moe_gemm_kernel<1>, hipFuncAttributeMaxDynamicSharedMemorySize, 98304);
    hipFuncSetAttribute((const void*)moe_gemm_kernel<2>, hipFuncAttributeMaxDynamicSharedMemorySize, 98304);

    router_kernel<<<dim3(RBLOCKS), 256, 0, stream>>>(x, wr, xb, tok_e, tok_w, part_p, part_c);
    transpose_bf16_kernel<<<dim3(HDIM / 32, DDIM / 32, NEXP), 256, 0, stream>>>(w1, w1t, DDIM, HDIM);
    transpose_bf16_kernel<<<dim3(DDIM / 32, HDIM / 32, NEXP), 256, 0, stream>>>(w2, w2t, HDIM, DDIM);
    finalize_kernel<<<dim3(1), 256, 0, stream>>>(part_p, part_c, counts, offs, out + (size_t)N_TOK * DDIM);
    scatter_kernel<<<dim3(SBLOCKS), 256, 0, stream>>>(tok_e, tok_w, offs, cursors, slot_token, slot_w);
    moe_gemm_kernel<1><<<dim3(HDIM / 256, N_TOK / 256, NEXP), 512, 98304, stream>>>(
        xb, w1t, hbuf, nullptr, slot_token, slot_w, offs, counts);
    moe_gemm_kernel<2><<<dim3(DDIM / 256, N_TOK / 256, NEXP), 512, 98304, stream>>>(
        hbuf, w2t, nullptr, out, slot_token, slot_w, offs, counts);
}

// Round 16
// 484.436 us; speedup vs baseline: 1.1381x; 1.1381x over previous
//
#include <hip/hip_runtime.h>

#define N_TOK 8192
#define DDIM  1024
#define HDIM  4096
#define NEXP  6
#define RBLOCKS (N_TOK / 4)
#define SBLOCKS 32

typedef unsigned short ushort_t;
typedef __bf16 bf16_t;
typedef bf16_t bf16x8 __attribute__((ext_vector_type(8)));
typedef float f32x4 __attribute__((ext_vector_type(4)));

typedef const __attribute__((address_space(1))) void* gptr_t;
typedef __attribute__((address_space(3))) void* lptr_t;

__device__ __forceinline__ void g2l16(const void* g, void* l) {
    __builtin_amdgcn_global_load_lds((gptr_t)g, (lptr_t)l, 16, 0, 0);
}

__device__ __forceinline__ ushort_t f2bf(float f) {
    unsigned int u = __float_as_uint(f);
    unsigned int r = (u + 0x7FFFu + ((u >> 16) & 1u)) >> 16;
    return (ushort_t)r;
}

// ---------------- transpose + convert: src (R,C) fp32 -> dst (C,R) bf16, per expert z ----------------
__global__ void transpose_bf16_kernel(const float* __restrict__ src, ushort_t* __restrict__ dst,
                                      int R, int C) {
    __shared__ float tile[32][33];
    size_t msz = (size_t)R * C;
    src += (size_t)blockIdx.z * msz;
    dst += (size_t)blockIdx.z * msz;
    int c0 = blockIdx.x * 32, r0 = blockIdx.y * 32;
    int tx = threadIdx.x & 31, ty = threadIdx.x >> 5;
#pragma unroll
    for (int i = 0; i < 4; ++i)
        tile[ty + 8 * i][tx] = src[(size_t)(r0 + ty + 8 * i) * C + c0 + tx];
    __syncthreads();
#pragma unroll
    for (int i = 0; i < 4; ++i)
        dst[(size_t)(c0 + ty + 8 * i) * R + r0 + tx] = f2bf(tile[tx][ty + 8 * i]);
}

// ---------------- router (also emits xb = bf16(x)) ----------------
__global__ void router_kernel(const float* __restrict__ x, const float* __restrict__ wr,
                              ushort_t* __restrict__ xb,
                              int* __restrict__ tok_e, float* __restrict__ tok_w,
                              float* __restrict__ part_p, int* __restrict__ part_c) {
    __shared__ float bsum[NEXP];
    __shared__ int bcnt[NEXP];
    int wid = threadIdx.x >> 6, l = threadIdx.x & 63;
    if (threadIdx.x < NEXP) { bsum[threadIdx.x] = 0.f; bcnt[threadIdx.x] = 0; }
    __syncthreads();
    int t = blockIdx.x * 4 + wid;
    const float* xr = x + (size_t)t * DDIM;
    ushort_t* xbr = xb + (size_t)t * DDIM;
    float acc[NEXP] = {0.f, 0.f, 0.f, 0.f, 0.f, 0.f};
#pragma unroll
    for (int c = 0; c < 4; ++c) {
        int k0 = c * 256 + l * 4;
        float4 xv = *(const float4*)(xr + k0);
        union { ushort_t u[4]; uint2 v; } ob;
        ob.u[0] = f2bf(xv.x); ob.u[1] = f2bf(xv.y); ob.u[2] = f2bf(xv.z); ob.u[3] = f2bf(xv.w);
        *(uint2*)(xbr + k0) = ob.v;
        float wv[24];
#pragma unroll
        for (int q = 0; q < 6; ++q)
            *(float4*)(wv + 4 * q) = *(const float4*)(wr + (size_t)k0 * NEXP + 4 * q);
        float xa[4] = {xv.x, xv.y, xv.z, xv.w};
#pragma unroll
        for (int r = 0; r < 4; ++r)
#pragma unroll
            for (int e = 0; e < NEXP; ++e) acc[e] += xa[r] * wv[r * NEXP + e];
    }
#pragma unroll
    for (int e = 0; e < NEXP; ++e)
#pragma unroll
        for (int d = 32; d >= 1; d >>= 1) acc[e] += __shfl_xor(acc[e], d);
    if (l == 0) {
        float m = acc[0];
#pragma unroll
        for (int e = 1; e < NEXP; ++e) m = fmaxf(m, acc[e]);
        float p[NEXP], s = 0.f;
#pragma unroll
        for (int e = 0; e < NEXP; ++e) { p[e] = expf(acc[e] - m); s += p[e]; }
        float inv = 1.0f / s;
#pragma unroll
        for (int e = 0; e < NEXP; ++e) p[e] *= inv;
        int i1 = 0; float b1 = p[0];
#pragma unroll
        for (int e = 1; e < NEXP; ++e) if (p[e] > b1) { b1 = p[e]; i1 = e; }
        int i2 = -1; float b2 = -1.f;
#pragma unroll
        for (int e = 0; e < NEXP; ++e) if (e != i1 && p[e] > b2) { b2 = p[e]; i2 = e; }
        float swn = 1.0f / (b1 + b2);
        tok_e[2 * t] = i1; tok_e[2 * t + 1] = i2;
        tok_w[2 * t] = b1 * swn; tok_w[2 * t + 1] = b2 * swn;
        atomicAdd(&bcnt[i1], 1);
        atomicAdd(&bcnt[i2], 1);
#pragma unroll
        for (int e = 0; e < NEXP; ++e) atomicAdd(&bsum[e], p[e]);
    }
    __syncthreads();
    if (threadIdx.x < NEXP) {
        part_p[(size_t)blockIdx.x * NEXP + threadIdx.x] = bsum[threadIdx.x];
        part_c[(size_t)blockIdx.x * NEXP + threadIdx.x] = bcnt[threadIdx.x];
    }
}

// ---------------- finalize ----------------
__global__ void finalize_kernel(const float* __restrict__ part_p, const int* __restrict__ part_c,
                                int* __restrict__ counts, int* __restrict__ offs,
                                float* __restrict__ aux_out) {
    __shared__ float redp[NEXP][4];
    __shared__ int redc[NEXP][4];
    int tid = threadIdx.x, wid = tid >> 6, l = tid & 63;
    float myp[NEXP] = {0.f, 0.f, 0.f, 0.f, 0.f, 0.f};
    int myc[NEXP] = {0, 0, 0, 0, 0, 0};
    for (int b = tid; b < RBLOCKS; b += 256) {
#pragma unroll
        for (int e = 0; e < NEXP; ++e) {
            myp[e] += part_p[(size_t)b * NEXP + e];
            myc[e] += part_c[(size_t)b * NEXP + e];
        }
    }
#pragma unroll
    for (int e = 0; e < NEXP; ++e) {
#pragma unroll
        for (int d = 32; d >= 1; d >>= 1) {
            myp[e] += __shfl_xor(myp[e], d);
            myc[e] += __shfl_xor(myc[e], d);
        }
        if (l == 0) { redp[e][wid] = myp[e]; redc[e][wid] = myc[e]; }
    }
    __syncthreads();
    if (tid == 0) {
        int o = 0;
        float s = 0.f;
        for (int e = 0; e < NEXP; ++e) {
            int c = redc[e][0] + redc[e][1] + redc[e][2] + redc[e][3];
            float ps = redp[e][0] + redp[e][1] + redp[e][2] + redp[e][3];
            counts[e] = c;
            offs[e] = o;
            o += c;
            float d = ps / (float)N_TOK - (1.0f / 6.0f);
            s += d * d;
        }
        offs[NEXP] = o;
        aux_out[0] = 0.01f * (s / 6.0f);
    }
}

// ---------------- scatter ----------------
__global__ void scatter_kernel(const int* __restrict__ tok_e, const float* __restrict__ tok_w,
                               const int* __restrict__ offs, int* __restrict__ cursors,
                               int* __restrict__ slot_token, float* __restrict__ slot_w) {
    __shared__ int lcnt[NEXP], lbase[NEXP];
    int tid = threadIdx.x;
    if (tid < NEXP) lcnt[tid] = 0;
    __syncthreads();
    int t = blockIdx.x * 256 + tid;
    int e0 = tok_e[2 * t], e1 = tok_e[2 * t + 1];
    int r0 = atomicAdd(&lcnt[e0], 1);
    int r1 = atomicAdd(&lcnt[e1], 1);
    __syncthreads();
    if (tid < NEXP) lbase[tid] = atomicAdd(&cursors[tid], lcnt[tid]);
    __syncthreads();
    int i0 = offs[e0] + lbase[e0] + r0;
    slot_token[i0] = t; slot_w[i0] = tok_w[2 * t];
    int i1 = offs[e1] + lbase[e1] + r1;
    slot_token[i1] = t; slot_w[i1] = tok_w[2 * t + 1];
}

// ---- MoE GEMM: 128M x 256N tile, BK=32, 256 thr / 4 waves (2M x 2N), wave-tile 64x128 ----
// Session-best structure (R7/R14, 486-488 us): depth-2 prefetch pipeline, 3 LDS buffers
// (24KB each), counted vmcnt(6) (never 0 mid-loop), one raw barrier per K-step,
// zero-conflict swizzle, 2 blocks/CU (the inter-block overlap is load-bearing — R15).
// LAYER 1: h = gelu(gather(x) @ w1t^T), Kd=1024, Nd=4096
// LAYER 2: out += w * (hbuf @ w2t^T),   Kd=4096, Nd=1024

#define STAGE(BI, KTE) do { \
    ushort_t* bA_ = sbase + (BI) * 12288; \
    ushort_t* bB_ = bA_ + 4096; \
    g2l16(A + aoff[0] + (KTE),   bA_ + wid * 512); \
    g2l16(A + aoff[1] + (KTE),   bA_ + 2048 + wid * 512); \
    g2l16(Bte + boff[0] + (KTE), bB_ + wid * 512); \
    g2l16(Bte + boff[1] + (KTE), bB_ + 2048 + wid * 512); \
    g2l16(Bte + boff[2] + (KTE), bB_ + 4096 + wid * 512); \
    g2l16(Bte + boff[3] + (KTE), bB_ + 6144 + wid * 512); \
  } while (0)

template <int LAYER>
__global__ __launch_bounds__(256, 2)
void moe_gemm_kernel(const ushort_t* __restrict__ A, const ushort_t* __restrict__ Bt,
                     ushort_t* __restrict__ Hout, float* __restrict__ Out,
                     const int* __restrict__ slot_token, const float* __restrict__ slot_w,
                     const int* __restrict__ offs, const int* __restrict__ counts) {
    constexpr int Kd = (LAYER == 1) ? DDIM : HDIM;
    constexpr int Nd = (LAYER == 1) ? HDIM : DDIM;
    constexpr int NT = Kd / 32;
    extern __shared__ __align__(16) char smem[];
    ushort_t* sbase = (ushort_t*)smem;          // 3 buffers x 12288 elems (A 4096 + B 8192)

    const int e = blockIdx.z;
    const int cnt = counts[e];
    const int mbase = blockIdx.y * 128;
    if (mbase >= cnt) return;                    // block-uniform: safe with raw barriers
    const int nbase = blockIdx.x * 256;
    const int off = offs[e];
    const ushort_t* Bte = Bt + (size_t)e * ((size_t)Nd * Kd);

    const int tid = threadIdx.x;
    const int wid = tid >> 6, l = tid & 63;

    // ---- staging sources (chunk = 8 elems = 16B; cs pre-swizzled, LDS dest linear) ----
    size_t aoff[2];
#pragma unroll
    for (int j = 0; j < 2; ++j) {
        int p = j * 256 + tid;
        int row = p >> 2, slot = p & 3;
        int cs = slot ^ ((row >> 1) & 3);
        int gr = mbase + row;
        int grc = gr < cnt - 1 ? gr : cnt - 1;
        size_t arow = (LAYER == 1) ? (size_t)slot_token[off + grc] * DDIM
                                   : (size_t)(off + grc) * HDIM;
        aoff[j] = arow + (size_t)cs * 8;
    }
    size_t boff[4];
#pragma unroll
    for (int j = 0; j < 4; ++j) {
        int p = j * 256 + tid;
        int row = p >> 2, slot = p & 3;
        int cs = slot ^ ((row >> 1) & 3);
        boff[j] = (size_t)(nbase + row) * Kd + (size_t)cs * 8;
    }

    // ---- fragment read byte-offsets (swizzled to match) ----
    const int lm = l & 15, kg = l >> 4;
    const int wm = (wid & 1) * 64, wn = (wid >> 1) * 128;
    int aOffs[4], bOffs[8];
#pragma unroll
    for (int fr = 0; fr < 4; ++fr) {
        int ar = wm + fr * 16 + lm;
        aOffs[fr] = ar * 64 + ((kg ^ ((ar >> 1) & 3)) << 4);
    }
#pragma unroll
    for (int fr = 0; fr < 8; ++fr) {
        int br = wn + fr * 16 + lm;
        bOffs[fr] = br * 64 + ((kg ^ ((br >> 1) & 3)) << 4);
    }

    f32x4 acc[4][8] = {};

    // ---- prologue: stage tiles 0 and 1 ----
    STAGE(0, 0);
    STAGE(1, 32);
    asm volatile("s_waitcnt vmcnt(6)" ::: "memory");   // tile 0 resident
    __builtin_amdgcn_sched_barrier(0);
    __builtin_amdgcn_s_barrier();

    int rb = 0;
    for (int t = 0; t < NT; ++t) {
        int sb = rb + 2; if (sb >= 3) sb -= 3;
        if (t + 2 < NT) STAGE(sb, (t + 2) * 32);
        const char* bA = (const char*)(sbase + rb * 12288);
        const char* bB = bA + 8192;
        bf16x8 af[4], bfv[8];
#pragma unroll
        for (int fr = 0; fr < 4; ++fr) af[fr] = *(const bf16x8*)(bA + aOffs[fr]);
#pragma unroll
        for (int fr = 0; fr < 8; ++fr) bfv[fr] = *(const bf16x8*)(bB + bOffs[fr]);
#pragma unroll
        for (int i = 0; i < 4; ++i)
#pragma unroll
            for (int n = 0; n < 8; ++n)
                acc[i][n] = __builtin_amdgcn_mfma_f32_16x16x32_bf16(af[i], bfv[n], acc[i][n], 0, 0, 0);
        if (t < NT - 1) {
            if (t + 3 <= NT) { asm volatile("s_waitcnt vmcnt(6)" ::: "memory"); }
            else             { asm volatile("s_waitcnt vmcnt(0)" ::: "memory"); }
            __builtin_amdgcn_sched_barrier(0);
            __builtin_amdgcn_s_barrier();
        }
        rb = rb + 1; if (rb >= 3) rb -= 3;
    }

    // ---- epilogue. C/D: col = lane&15, row = (lane>>4)*4 + reg ----
    if (LAYER == 1) {
#pragma unroll
        for (int i = 0; i < 4; ++i) {
#pragma unroll
            for (int r = 0; r < 4; ++r) {
                int grow = mbase + wm + i * 16 + kg * 4 + r;
                if (grow < cnt) {
                    size_t hbase = (size_t)(off + grow) * HDIM + nbase + wn + lm;
#pragma unroll
                    for (int n = 0; n < 8; ++n) {
                        float v = acc[i][n][r];
                        float u = -1.5957691216f * v * (1.0f + 0.044715f * v * v);
                        float g = v / (1.0f + __expf(u));
                        Hout[hbase + n * 16] = f2bf(g);
                    }
                }
            }
        }
    } else {
#pragma unroll
        for (int i = 0; i < 4; ++i) {
#pragma unroll
            for (int r = 0; r < 4; ++r) {
                int grow = mbase + wm + i * 16 + kg * 4 + r;
                if (grow < cnt) {
                    int si = off + grow;
                    int tok = slot_token[si];
                    float wgt = slot_w[si];
                    float* obase = Out + (size_t)tok * DDIM + nbase + wn + lm;
#pragma unroll
                    for (int n = 0; n < 8; ++n)
                        atomicAdd(obase + n * 16, wgt * acc[i][n][r]);
                }
            }
        }
    }
}
#undef STAGE

extern "C" void kernel_launch(void* const* d_in, const int* in_sizes, int n_in,
                              void* d_out, int out_size, void* d_ws, size_t ws_size,
                              hipStream_t stream) {
    const float* x  = (const float*)d_in[0];
    const float* wr = (const float*)d_in[1];
    const float* w1 = (const float*)d_in[2];
    const float* w2 = (const float*)d_in[3];
    float* out = (float*)d_out;

    char* ws = (char*)d_ws;
    size_t o = 0;
    ushort_t* xb   = (ushort_t*)(ws + o); o += (size_t)N_TOK * DDIM * 2;
    ushort_t* w1t  = (ushort_t*)(ws + o); o += (size_t)NEXP * HDIM * DDIM * 2;
    ushort_t* w2t  = (ushort_t*)(ws + o); o += (size_t)NEXP * DDIM * HDIM * 2;
    ushort_t* hbuf = (ushort_t*)(ws + o); o += (size_t)2 * N_TOK * HDIM * 2;
    int*   tok_e   = (int*)(ws + o);   o += (size_t)N_TOK * 2 * 4;
    float* tok_w   = (float*)(ws + o); o += (size_t)N_TOK * 2 * 4;
    int*   slot_token = (int*)(ws + o);   o += (size_t)2 * N_TOK * 4;
    float* slot_w     = (float*)(ws + o); o += (size_t)2 * N_TOK * 4;
    float* part_p  = (float*)(ws + o); o += (size_t)RBLOCKS * NEXP * 4;
    int*   part_c  = (int*)(ws + o);   o += (size_t)RBLOCKS * NEXP * 4;
    int*   counts  = (int*)(ws + o);   o += 32;
    int*   cursors = (int*)(ws + o);   o += 32;
    int*   offs    = (int*)(ws + o);   o += 32;

    hipMemsetAsync(d_out, 0, (size_t)out_size * sizeof(float), stream);
    hipMemsetAsync(cursors, 0, 32, stream);

    hipFuncSetAttribute((const void*)moe_gemm_kernel<1>, hipFuncAttributeMaxDynamicSharedMemorySize, 73728);
    hipFuncSetAttribute((const void*)moe_gemm_kernel<2>, hipFuncAttributeMaxDynamicSharedMemorySize, 73728);

    router_kernel<<<dim3(RBLOCKS), 256, 0, stream>>>(x, wr, xb, tok_e, tok_w, part_p, part_c);
    transpose_bf16_kernel<<<dim3(HDIM / 32, DDIM / 32, NEXP), 256, 0, stream>>>(w1, w1t, DDIM, HDIM);
    transpose_bf16_kernel<<<dim3(DDIM / 32, HDIM / 32, NEXP), 256, 0, stream>>>(w2, w2t, HDIM, DDIM);
    finalize_kernel<<<dim3(1), 256, 0, stream>>>(part_p, part_c, counts, offs, out + (size_t)N_TOK * DDIM);
    scatter_kernel<<<dim3(SBLOCKS), 256, 0, stream>>>(tok_e, tok_w, offs, cursors, slot_token, slot_w);
    moe_gemm_kernel<1><<<dim3(HDIM / 256, N_TOK / 128, NEXP), 256, 73728, stream>>>(
        xb, w1t, hbuf, nullptr, slot_token, slot_w, offs, counts);
    moe_gemm_kernel<2><<<dim3(DDIM / 256, N_TOK / 128, NEXP), 256, 73728, stream>>>(
        hbuf, w2t, nullptr, out, slot_token, slot_w, offs, counts);
}